// Round 5
// baseline (563.917 us; speedup 1.0000x reference)
//
#include <hip/hip_runtime.h>

// Dense GEMM: C[M,N] = x[M,K] @ W[K,N] + bias[N], f32 in/out, bf16 MFMA compute.
// R8 = R7 rerun with __launch_bounds__(512,1): LDS (128KB) already caps
//     occupancy at 1 block/CU, so the ",2" hint only constrained regalloc
//     (~280 unified VGPRs needed > 256 cap -> inner-loop spills, suspected
//     container-killer). Design unchanged:
//     - x f32->bf16 fused into GEMM A-staging (reg-stage: issue f32 loads 2
//       phases early, cvt+ds_write before the publishing barrier).
//     - Prep is transpose-only. No Xbf round-trip.
//     - Mixed vmcnt ledger (B=2 gload_lds, A=4 f32 loads): vmcnt(6) exact.

#define MDIM 8192
#define NDIM 4096
#define KDIM 4096
#define BM 256
#define BN 256
#define BK 64
#define NKT (KDIM / BK)   // 64 K-tiles
#define NH  (KDIM / 32)   // 128 k-half tiles per operand

typedef __bf16 bf16x8 __attribute__((ext_vector_type(8)));
typedef float f32x4 __attribute__((ext_vector_type(4)));
typedef unsigned short u16x8 __attribute__((ext_vector_type(8)));

__device__ __forceinline__ unsigned short f32_to_bf16(float f) {
  union { float f; unsigned int u; } v; v.f = f;
  unsigned int r = 0x7FFFu + ((v.u >> 16) & 1u);  // round-to-nearest-even
  return (unsigned short)((v.u + r) >> 16);
}

// ---- prep: transpose W [K][N] f32 -> Wt [N][K] bf16 (4096 blocks) --------
__global__ __launch_bounds__(256) void prep_kernel(
    const float* __restrict__ W, unsigned short* __restrict__ Wt) {
  __shared__ __align__(16) unsigned short tile[64][72];
  const int tb = blockIdx.x;            // 64 n-tiles x 64 k-tiles
  const int t = threadIdx.x;
  const int n0 = (tb & 63) * 64;
  const int k0 = (tb >> 6) * 64;
#pragma unroll
  for (int p = 0; p < 4; p++) {
    const int kk = p * 16 + (t >> 4);
    const int nl = (t & 15) * 4;
    float4 v = *(const float4*)(W + (size_t)(k0 + kk) * NDIM + n0 + nl);
    tile[nl + 0][kk] = f32_to_bf16(v.x);
    tile[nl + 1][kk] = f32_to_bf16(v.y);
    tile[nl + 2][kk] = f32_to_bf16(v.z);
    tile[nl + 3][kk] = f32_to_bf16(v.w);
  }
  __syncthreads();
#pragma unroll
  for (int q = 0; q < 2; q++) {
    const int nl = q * 32 + (t >> 3);
    const int kl = (t & 7) * 8;
    *(u16x8*)(Wt + (size_t)(n0 + nl) * KDIM + k0 + kl) =
        *(const u16x8*)(&tile[nl][kl]);
  }
}

// ---- GEMM ---------------------------------------------------------------
#define GLD_TO_LDS(g, l)                                                      \
  __builtin_amdgcn_global_load_lds(                                           \
      (const __attribute__((address_space(1))) void*)(g),                     \
      (__attribute__((address_space(3))) void*)(l), 16, 0, 0)

__global__ __launch_bounds__(512, 1) void gemm_bf16_kernel(
    const float* __restrict__ X,            // M x K f32 (cvt in-kernel)
    const unsigned short* __restrict__ Bt,  // N x K bf16
    const float* __restrict__ bias,
    float* __restrict__ C) {
  // 4 ring slots per operand; slot = k-half tile [256 rows][32 k] bf16.
  // Chunk swizzle: LDS chunk c' holds global chunk c'^((row>>1)&3).
  __shared__ __align__(16) unsigned short As[4 * 8192];  // 64 KB
  __shared__ __align__(16) unsigned short Bs[4 * 8192];  // 64 KB

  const int tid  = threadIdx.x;
  const int w    = tid >> 6;
  const int lane = tid & 63;

  // XCD mapping: 8 XCDs as 4(M) x 2(N) regions of 8x8 wgs (2048^2 of C).
  const int xcd   = blockIdx.x & 7;
  const int local = blockIdx.x >> 3;
  const int bm0 = ((xcd >> 1) * 8 + (local & 7)) * BM;
  const int bn0 = ((xcd & 1) * 8 + (local >> 3)) * BN;

  // Staging map: wave w covers rows [w*32, +32): row = w*32+j*16+(lane>>2),
  // chunk' = lane&3, source chunk = (lane&3)^((lane>>3)&3).
  const int stR = w * 32 + (lane >> 2);
  const int cSw = ((lane & 3) ^ ((lane >> 3) & 3)) * 8;   // k-elem offset
  const float* xA0 = X + (size_t)(bm0 + stR) * KDIM + cSw;
  const float* xA1 = xA0 + (size_t)16 * KDIM;
  const unsigned short* sB0 = Bt + (size_t)(bn0 + stR) * KDIM + cSw;
  const unsigned short* sB1 = sB0 + (size_t)16 * KDIM;
  unsigned short* ldsA = As + w * 1024;   // +slot*8192 (+512 for j=1)
  unsigned short* ldsB = Bs + w * 1024;

  // Compute map: wave (wr,wc) owns 128x64 at (wr*128, wc*64).
  const int wr = w >> 2;
  const int wc = w & 3;
  const int pa = (lane & 15) * 32 + (((lane >> 4) ^ ((lane >> 1) & 3))) * 8;
  const unsigned short* aBase = As + (wr * 128) * 32 + pa;
  const unsigned short* bBase = Bs + (wc * 64) * 32 + pa;

  f32x4 acc[8][4] = {};
  float4 rs0[4], rs1[4];   // 2-deep A reg pipeline (static names, rule #20)

  auto stageB = [&](int h) {               // 2 vmem ops
    const int koff = (h < NH) ? h * 32 : 0;
    const int sb = (h & 3) * 8192;
    GLD_TO_LDS(sB0 + koff, ldsB + sb);
    GLD_TO_LDS(sB1 + koff, ldsB + sb + 512);
  };

#define ISSUE_A(h, dst)                                                       \
  {                                                                           \
    const int koff_ = ((h) < NH) ? (h) * 32 : 0;                              \
    dst[0] = *(const float4*)(xA0 + koff_);                                   \
    dst[1] = *(const float4*)(xA0 + koff_ + 4);                               \
    dst[2] = *(const float4*)(xA1 + koff_);                                   \
    dst[3] = *(const float4*)(xA1 + koff_ + 4);                               \
  }

#define WRITE_A(h, src)                                                       \
  {                                                                           \
    const int sb_ = ((h) & 3) * 8192;                                         \
    u16x8 o0, o1;                                                             \
    o0[0] = f32_to_bf16(src[0].x); o0[1] = f32_to_bf16(src[0].y);             \
    o0[2] = f32_to_bf16(src[0].z); o0[3] = f32_to_bf16(src[0].w);             \
    o0[4] = f32_to_bf16(src[1].x); o0[5] = f32_to_bf16(src[1].y);             \
    o0[6] = f32_to_bf16(src[1].z); o0[7] = f32_to_bf16(src[1].w);             \
    o1[0] = f32_to_bf16(src[2].x); o1[1] = f32_to_bf16(src[2].y);             \
    o1[2] = f32_to_bf16(src[2].z); o1[3] = f32_to_bf16(src[2].w);             \
    o1[4] = f32_to_bf16(src[3].x); o1[5] = f32_to_bf16(src[3].y);             \
    o1[6] = f32_to_bf16(src[3].z); o1[7] = f32_to_bf16(src[3].w);             \
    *(u16x8*)(ldsA + sb_ + lane * 8) = o0;                                    \
    *(u16x8*)(ldsA + sb_ + 512 + lane * 8) = o1;                              \
  }

#define MFMA16(ACC0)                                                          \
  _Pragma("unroll") for (int m = 0; m < 4; ++m)                               \
    _Pragma("unroll") for (int n = 0; n < 4; ++n)                             \
      acc[(ACC0) + m][n] = __builtin_amdgcn_mfma_f32_16x16x32_bf16(           \
          aF[m], bF[n], acc[(ACC0) + m][n], 0, 0, 0);

  // Prologue: A0,A1 direct-written; B0,B1 via gload_lds; A2 left in flight.
  ISSUE_A(0, rs0)
  ISSUE_A(1, rs1)
  stageB(0);
  stageB(1);
  asm volatile("s_waitcnt vmcnt(0)" ::: "memory");
  __builtin_amdgcn_sched_barrier(0);
  WRITE_A(0, rs0)
  WRITE_A(1, rs1)
  ISSUE_A(2, rs1)                       // p1 (kt=0) writes rs1 = A2
  asm volatile("s_waitcnt lgkmcnt(0)" ::: "memory");
  __builtin_amdgcn_sched_barrier(0);
  __builtin_amdgcn_s_barrier();
  __builtin_amdgcn_sched_barrier(0);

  // Ledger (steady state, per phase: [outstanding before wait] -> vmcnt(6)):
  //  p0: B(2)+A(4)+B(2)=8  -> retires old B  (published by this barrier)
  //  p1: A(4)+B(2)+A(4)=10 -> retires old A  (then ds_write it)
  //  p2,p3: same as p0,p1.  Uniform vmcnt(6) exact.
  for (int kt = 0; kt < NKT; ++kt) {
    const int s0 = ((2 * kt) & 3) * 8192;
    const int s1 = ((2 * kt + 1) & 3) * 8192;
    bf16x8 aF[4], bF[4];

#define PHASE_B(SLOT, STH)                                                    \
    {                                                                         \
      _Pragma("unroll") for (int f = 0; f < 4; ++f)                           \
        aF[f] = *(const bf16x8*)(aBase + (SLOT) + f * 512);                   \
      _Pragma("unroll") for (int f = 0; f < 4; ++f)                           \
        bF[f] = *(const bf16x8*)(bBase + (SLOT) + f * 512);                   \
      stageB(STH);                                                            \
      asm volatile("s_waitcnt vmcnt(6)" ::: "memory");                        \
      asm volatile("s_waitcnt lgkmcnt(0)" ::: "memory");                      \
      __builtin_amdgcn_sched_barrier(0);                                      \
      __builtin_amdgcn_s_barrier();                                           \
      __builtin_amdgcn_sched_barrier(0);                                      \
      __builtin_amdgcn_s_setprio(1);                                          \
      MFMA16(0)                                                               \
      __builtin_amdgcn_s_setprio(0);                                          \
    }

#define PHASE_A(SLOT, STH, WH, ISS, WRT)                                      \
    {                                                                         \
      _Pragma("unroll") for (int f = 0; f < 4; ++f)                           \
        aF[f] = *(const bf16x8*)(aBase + (SLOT) + 2048 + f * 512);            \
      ISSUE_A(STH, ISS)                                                       \
      asm volatile("s_waitcnt vmcnt(6)" ::: "memory");                        \
      __builtin_amdgcn_sched_barrier(0);                                      \
      WRITE_A(WH, WRT)                                                        \
      asm volatile("s_waitcnt lgkmcnt(0)" ::: "memory");                      \
      __builtin_amdgcn_sched_barrier(0);                                      \
      __builtin_amdgcn_s_barrier();                                           \
      __builtin_amdgcn_sched_barrier(0);                                      \
      __builtin_amdgcn_s_setprio(1);                                          \
      MFMA16(4)                                                               \
      __builtin_amdgcn_s_setprio(0);                                          \
    }

    // p0: (kh0,mh0)  stages B(2kt+2)
    PHASE_B(s0, 2 * kt + 2)
    // p1: (kh0,mh1)  issues A(2kt+3)->rs0, writes A(2kt+2) from rs1
    PHASE_A(s0, 2 * kt + 3, 2 * kt + 2, rs0, rs1)
    // p2: (kh1,mh0)  stages B(2kt+3)
    PHASE_B(s1, 2 * kt + 3)
    // p3: (kh1,mh1)  issues A(2kt+4)->rs1, writes A(2kt+3) from rs0
    PHASE_A(s1, 2 * kt + 4, 2 * kt + 3, rs1, rs0)
#undef PHASE_B
#undef PHASE_A
  }

  // Epilogue: C/D layout col = lane&15, row = quad*4 + reg  [m89/m91]
  const int quad = lane >> 4;
  const int lr   = lane & 15;
  const int om = bm0 + wr * 128 + quad * 4;
  const int on = bn0 + wc * 64 + lr;
#pragma unroll
  for (int n = 0; n < 4; ++n) {
    float bv = bias[on + n * 16];
#pragma unroll
    for (int m = 0; m < 8; ++m) {
      f32x4 v = acc[m][n];
#pragma unroll
      for (int r = 0; r < 4; ++r) {
        C[(size_t)(om + m * 16 + r) * NDIM + (on + n * 16)] = v[r] + bv;
      }
    }
  }
}

extern "C" void kernel_launch(void* const* d_in, const int* in_sizes, int n_in,
                              void* d_out, int out_size, void* d_ws, size_t ws_size,
                              hipStream_t stream) {
  const float* x    = (const float*)d_in[0];  // 8192 x 4096
  const float* w    = (const float*)d_in[1];  // 4096 x 4096 ([k][n])
  const float* bias = (const float*)d_in[2];  // 4096
  float* out = (float*)d_out;

  unsigned short* Wt = (unsigned short*)d_ws;  // 32 MB

  prep_kernel<<<4096, 256, 0, stream>>>(w, Wt);
  gemm_bf16_kernel<<<dim3((MDIM / BM) * (NDIM / BN)), 512, 0, stream>>>(
      x, Wt, bias, out);
}